// Round 7
// baseline (1126.070 us; speedup 1.0000x reference)
//
#include <hip/hip_runtime.h>

#define S_    4
#define E_    8
#define NPS   12500
#define AEVD  1008
#define D1    256
#define D2    192
#define D3    160
#define TM    64
#define NT    ((NPS + TM - 1) / TM)    // 196
#define TG    8                        // tiles per supergroup
#define NG    ((NT + TG - 1) / TG)     // 25
#define ALPHA 0.1f
#define RS    1024                     // gathered aev row length (bf16 elems, zero-padded)
#define NROW  (NT * TM)                // 12544 rows per species

// packed-weight geometry: [kb][nb][lane(64)][8] bf16, K padded to kb*32.
#define KB1 32
#define NB1 16
#define KB2 8
#define NB2 12
#define KB3 6
#define NB3 10

typedef __attribute__((ext_vector_type(8))) short short8;
typedef __attribute__((ext_vector_type(4))) float f32x4;

__device__ __forceinline__ ushort f2bf(float f) {
    unsigned u = __float_as_uint(f);
    unsigned r = u + 0x7FFFu + ((u >> 16) & 1u);   // RNE
    return (ushort)(r >> 16);
}
__device__ __forceinline__ float celu_f(float v) {
    return v > 0.0f ? v : ALPHA * (__expf(v * (1.0f / ALPHA)) - 1.0f);
}
// LDS-only barrier: outstanding global loads stay in flight.
__device__ __forceinline__ void sync_lds() {
    asm volatile("s_waitcnt lgkmcnt(0)" ::: "memory");
    __builtin_amdgcn_s_barrier();
}
// async global->LDS DMA, 16B/lane; LDS dest = wave-uniform base + lane*16
#define GLD16(g, lp) __builtin_amdgcn_global_load_lds( \
    (const __attribute__((address_space(1))) void*)(g), \
    (__attribute__((address_space(3))) void*)(lp), 16, 0, 0)
// Pin issue order: nothing may cross. Placed right after each GLD16 so the DMA is
// provably OLDER than the 4 loadB vector loads -> vmcnt(4) deterministically retires it.
// (Round-5/6 NaN root cause: scheduler reordered loadB above GLD16, breaking the count.)
#define SCHED0() __builtin_amdgcn_sched_barrier(0)

// ---------------- weight pre-pack: fp32 [se][K][N] -> bf16 fragment order ----------------
__device__ __forceinline__ void pack_body(const float* __restrict__ W, ushort* __restrict__ out,
                                          int Ksrc, int kbs, int nbs, int Nsrc, int b)
{
    const int kb = b % kbs;
    const int se = b / kbs;
    const int t  = threadIdx.x;
    const int l  = t & 63, q = t >> 6;
    const float* Wse = W + (size_t)se * Ksrc * Nsrc;
    for (int i = 0; i < 4; ++i) {
        int nb = q + i * 4;
        if (nb >= nbs) break;
        int n = nb * 16 + (l & 15);
        ushort v[8];
        #pragma unroll
        for (int j = 0; j < 8; ++j) {
            int k = kb * 32 + ((l >> 4) << 3) + j;
            float x = (k < Ksrc) ? Wse[(size_t)k * Nsrc + n] : 0.0f;
            v[j] = f2bf(x);
        }
        uint4 u;
        u.x = (unsigned)v[0] | ((unsigned)v[1] << 16);
        u.y = (unsigned)v[2] | ((unsigned)v[3] << 16);
        u.z = (unsigned)v[4] | ((unsigned)v[5] << 16);
        u.w = (unsigned)v[6] | ((unsigned)v[7] << 16);
        *(uint4*)(out + ((((size_t)se * kbs + kb) * nbs + nb) * 64 + l) * 8) = u;
    }
}

#define PACKB (S_ * E_ * (KB1 + KB2 + KB3))          // 1472
#define GATBS (NROW * (RS / 8) / 256)                // 6272 gather blocks per species
#define GATB  (GATBS * S_)                           // 25088

// prep = weight pack + aev gather/convert. Gather output: [s][12544 rows][1024] bf16,
// zero-padded at k>=1008 and padded atoms.
__global__ void prep(const float* __restrict__ W1, const float* __restrict__ W2,
                     const float* __restrict__ W3,
                     ushort* __restrict__ o1, ushort* __restrict__ o2, ushort* __restrict__ o3,
                     const float* __restrict__ aev, const int* __restrict__ idx,
                     ushort* __restrict__ aevb)
{
    int b = blockIdx.x;
    if (b < S_ * E_ * KB1)                  { pack_body(W1, o1, AEVD, KB1, NB1, D1, b); return; }
    b -= S_ * E_ * KB1;
    if (b < S_ * E_ * KB2)                  { pack_body(W2, o2, D1,   KB2, NB2, D2, b); return; }
    b -= S_ * E_ * KB2;
    if (b < S_ * E_ * KB3)                  { pack_body(W3, o3, D2,   KB3, NB3, D3, b); return; }
    b -= S_ * E_ * KB3;
    const int s    = b / GATBS;
    const int r    = (b % GATBS) * 256 + threadIdx.x;   // chunk id in species
    const int grow = r >> 7;                            // row 0..12543
    const int k0   = (r & 127) << 3;                    // 0,8,...,1016
    uint4 u = {0u, 0u, 0u, 0u};
    if (grow < NPS && k0 < AEVD) {
        const float* src = aev + (size_t)idx[s * NPS + grow] * AEVD + k0;
        float4 a = *(const float4*)(src);
        float4 c = *(const float4*)(src + 4);
        u.x = (unsigned)f2bf(a.x) | ((unsigned)f2bf(a.y) << 16);
        u.y = (unsigned)f2bf(a.z) | ((unsigned)f2bf(a.w) << 16);
        u.z = (unsigned)f2bf(c.x) | ((unsigned)f2bf(c.y) << 16);
        u.w = (unsigned)f2bf(c.z) | ((unsigned)f2bf(c.w) << 16);
    }
    *(uint4*)(aevb + ((size_t)s * NROW + grow) * RS + k0) = u;
}

// ---------------- fused 4-layer MFMA kernel ----------------
// Block mapping: XCD = blockIdx.x%8 is SPECIES-PURE (4 ensemble members of one species
// per XCD) -> 2.7 MB weights stay L2-resident across all supergroups.
// LDS: single 32 KB H1s buffer; Ast (8 KB, live only during L1) is ALIASED into
// H1s rows 48..63 (bytes 24576..32767); one sync_lds separates last Ast read from the
// epilogue overwrite. 32768 B/block -> 5 blocks/CU: latency-hiding x2 vs round 4.
// L1: n-split, async global_load_lds A-staging (counted vmcnt, sched_barrier-pinned).
// L2/L3: n-split, weights loaded once per block; H in LDS, XOR-swizzled cols.
// L4: masked partials + butterfly + cross-wave reduce.
__global__ __launch_bounds__(256, 5)
void ani_mfma(const ushort* __restrict__ aevb,
              const ushort* __restrict__ W1p, const ushort* __restrict__ W2p,
              const ushort* __restrict__ W3p,
              const float* __restrict__ b1, const float* __restrict__ b2,
              const float* __restrict__ b3,
              const float* __restrict__ W4, const float* __restrict__ b4,
              float* __restrict__ partials)
{
    const int bx   = blockIdx.x;
    const int r8   = bx & 7;                                   // XCD id (round-robin by linear id)
    const int se   = (r8 >> 1) * 8 + (r8 & 1) * 4 + ((bx >> 3) & 3);  // species-pure XCD
    const int ti   = bx >> 5;
    const int tile = blockIdx.y * TG + ti;
    if (tile >= NT) return;
    const int s = se >> 3;
    const int t = threadIdx.x;
    const int w = t >> 6, l = t & 63;
    const int lm = l & 15, kq = l >> 4;
    // Ast read swizzle (source-side pre-swizzled, as before)
    const int swz = (kq ^ ((lm >> 1) & 3)) << 3;

    __shared__ __align__(16) ushort H1s[TM * D1];       // 32768 B total (Ast + red aliased inside)
    ushort* Astb = &H1s[12288];                         // rows 48..63: Ast[2][64][32] (8 KB)

    const int aL  = l >> 2;
    const int gch = (l & 3) ^ ((l >> 3) & 3);
    const ushort* gsrc = aevb + ((size_t)s * NROW + (size_t)tile * TM + w * 16 + aL) * RS + gch * 8;
    ushort* lbase0 = Astb + (w * 16) * 32;              // buf 0
    ushort* lbase1 = Astb + 2048 + (w * 16) * 32;       // buf 1

    // ================= Layer 1: n-split, async DMA A-staging =================
    const ushort* w1se = W1p + (size_t)se * (KB1 * NB1 * 512);
    const ushort* bptr = w1se + ((size_t)(w * 4) * 64 + l) * 8;

    f32x4 acc1[4][4];
    #pragma unroll
    for (int mi = 0; mi < 4; ++mi)
        #pragma unroll
        for (int j = 0; j < 4; ++j) acc1[mi][j] = (f32x4){0.f, 0.f, 0.f, 0.f};

    uint4 B0[4], B1[4];
    auto loadB = [&](uint4* Bt, int kb) {
        #pragma unroll
        for (int i = 0; i < 4; ++i)
            Bt[i] = *(const uint4*)(bptr + (size_t)kb * (NB1 * 512) + i * 512);
    };
    auto mfma16 = [&](const ushort* Ab, uint4* Bt) {
        #pragma unroll
        for (int mi = 0; mi < 4; ++mi) {
            short8 af = *(const short8*)&Ab[(mi * 16 + lm) * 32 + swz];
            #pragma unroll
            for (int j = 0; j < 4; ++j)
                acc1[mi][j] = __builtin_amdgcn_mfma_f32_16x16x32_bf16(af, *(short8*)&Bt[j], acc1[mi][j], 0, 0, 0);
        }
    };

    GLD16(gsrc, lbase0);
    SCHED0();                                // DMA(0) provably before loadB(B0,0)
    loadB(B0, 0);
    for (int kb = 0; kb < KB1; kb += 2) {
        asm volatile("s_waitcnt vmcnt(4)" ::: "memory");   // retires DMA(kb): exactly 4 newer loads
        __builtin_amdgcn_s_barrier();
        GLD16(gsrc + (kb + 1) * 32, lbase1);
        SCHED0();                            // DMA(kb+1) before loadB(B1,kb+1)
        loadB(B1, kb + 1);
        mfma16(Astb, B0);
        asm volatile("s_waitcnt vmcnt(4)" ::: "memory");   // retires DMA(kb+1)
        __builtin_amdgcn_s_barrier();
        if (kb + 2 < KB1) {
            GLD16(gsrc + (kb + 2) * 32, lbase0);
            SCHED0();                        // DMA(kb+2) before loadB(B0,kb+2)
            loadB(B0, kb + 2);
        }
        mfma16(Astb + 2048, B1);
    }
    sync_lds();   // all Ast reads drained everywhere -> safe to overwrite rows 48..63

    // L1 epilogue: bias+celu -> H1 (atom-major bf16, swizzled cols)
    #pragma unroll
    for (int j = 0; j < 4; ++j) {
        int n = (w * 4 + j) * 16 + lm;
        float bias = b1[se * D1 + n];
        #pragma unroll
        for (int mi = 0; mi < 4; ++mi)
            #pragma unroll
            for (int r = 0; r < 4; ++r) {
                int row = mi * 16 + kq * 4 + r;
                H1s[row * D1 + (n ^ ((4 * (kq & 1) + r) << 3))] = f2bf(celu_f(acc1[mi][j][r] + bias));
            }
    }
    sync_lds();   // H1 visible to all waves

    // ================= Layer 2: n-split, weights loaded once per block =================
    const int hxA = (lm & 7) << 3;          // (row&7)<<3 for rows mi*16+lm
    const int nbase = w * 3;                // this wave's feature-block start (L2: exact; L3: clamped)
    const ushort* w2se = W2p + (size_t)se * (KB2 * NB2 * 512);

    f32x4 acc2[4][3];
    #pragma unroll
    for (int mi = 0; mi < 4; ++mi)
        #pragma unroll
        for (int i = 0; i < 3; ++i) acc2[mi][i] = (f32x4){0.f, 0.f, 0.f, 0.f};

    {
        uint4 Wb0[3], Wb1[3];
        short8 Ah0[4], Ah1[4];
        auto LW2 = [&](uint4* d, int kb) {
            #pragma unroll
            for (int i = 0; i < 3; ++i)
                d[i] = *(const uint4*)(w2se + ((size_t)(kb * NB2 + nbase + i) * 64 + l) * 8);
        };
        auto LA1 = [&](short8* d, int kb) {
            #pragma unroll
            for (int mi = 0; mi < 4; ++mi)
                d[mi] = *(const short8*)&H1s[(mi * 16 + lm) * D1 + ((kb * 32 + kq * 8) ^ hxA)];
        };
        LW2(Wb0, 0); LA1(Ah0, 0);
        #pragma unroll
        for (int kb = 0; kb < KB2; kb += 2) {
            LW2(Wb1, kb + 1); LA1(Ah1, kb + 1);
            #pragma unroll
            for (int mi = 0; mi < 4; ++mi)
                #pragma unroll
                for (int i = 0; i < 3; ++i)
                    acc2[mi][i] = __builtin_amdgcn_mfma_f32_16x16x32_bf16(Ah0[mi], *(short8*)&Wb0[i], acc2[mi][i], 0, 0, 0);
            if (kb + 2 < KB2) { LW2(Wb0, kb + 2); LA1(Ah0, kb + 2); }
            #pragma unroll
            for (int mi = 0; mi < 4; ++mi)
                #pragma unroll
                for (int i = 0; i < 3; ++i)
                    acc2[mi][i] = __builtin_amdgcn_mfma_f32_16x16x32_bf16(Ah1[mi], *(short8*)&Wb1[i], acc2[mi][i], 0, 0, 0);
        }
    }
    __syncthreads();                        // all H1 reads complete -> safe to overwrite (alias)

    // L2 epilogue: H2 = celu(acc2+b2), bf16, aliased over H1s[0..24K), swizzled cols
    ushort* H2 = H1s;                       // [64][192], row stride D2 (12288 ushorts total)
    #pragma unroll
    for (int i = 0; i < 3; ++i) {
        int n2 = (nbase + i) * 16 + lm;
        float bias = b2[se * D2 + n2];
        #pragma unroll
        for (int mi = 0; mi < 4; ++mi)
            #pragma unroll
            for (int r = 0; r < 4; ++r) {
                int row = mi * 16 + kq * 4 + r;
                H2[row * D2 + (n2 ^ ((4 * (kq & 1) + r) << 3))] = f2bf(celu_f(acc2[mi][i][r] + bias));
            }
    }
    __syncthreads();                        // H2 complete

    // ================= Layer 3: n-split (10 nb over 4 waves; dup-clamped, masked in L4) ====
    const ushort* w3se = W3p + (size_t)se * (KB3 * NB3 * 512);

    f32x4 acc3[4][3];
    #pragma unroll
    for (int mi = 0; mi < 4; ++mi)
        #pragma unroll
        for (int i = 0; i < 3; ++i) acc3[mi][i] = (f32x4){0.f, 0.f, 0.f, 0.f};

    {
        uint4 Wc0[3], Wc1[3];
        short8 Bh0[4], Bh1[4];
        auto LW3 = [&](uint4* d, int kb) {
            #pragma unroll
            for (int i = 0; i < 3; ++i) {
                int nb = nbase + i; nb = nb < NB3 ? nb : NB3 - 1;   // clamp duplicates
                d[i] = *(const uint4*)(w3se + ((size_t)(kb * NB3 + nb) * 64 + l) * 8);
            }
        };
        auto LA2 = [&](short8* d, int kb) {
            #pragma unroll
            for (int mi = 0; mi < 4; ++mi)
                d[mi] = *(const short8*)&H2[(mi * 16 + lm) * D2 + ((kb * 32 + kq * 8) ^ hxA)];
        };
        LW3(Wc0, 0); LA2(Bh0, 0);
        #pragma unroll
        for (int kb = 0; kb < KB3; kb += 2) {
            LW3(Wc1, kb + 1); LA2(Bh1, kb + 1);
            #pragma unroll
            for (int mi = 0; mi < 4; ++mi)
                #pragma unroll
                for (int i = 0; i < 3; ++i)
                    acc3[mi][i] = __builtin_amdgcn_mfma_f32_16x16x32_bf16(Bh0[mi], *(short8*)&Wc0[i], acc3[mi][i], 0, 0, 0);
            if (kb + 2 < KB3) { LW3(Wc0, kb + 2); LA2(Bh0, kb + 2); }
            #pragma unroll
            for (int mi = 0; mi < 4; ++mi)
                #pragma unroll
                for (int i = 0; i < 3; ++i)
                    acc3[mi][i] = __builtin_amdgcn_mfma_f32_16x16x32_bf16(Bh1[mi], *(short8*)&Wc1[i], acc3[mi][i], 0, 0, 0);
        }
    }

    // ================= Layer 4: masked partials + butterfly + cross-wave reduce ==========
    f32x4 s0 = {0,0,0,0}, s1 = {0,0,0,0}, s2 = {0,0,0,0}, s3 = {0,0,0,0};
    #pragma unroll
    for (int i = 0; i < 3; ++i) {
        bool valid = (nbase + i) < NB3;                  // mask dup-clamped blocks
        int n3 = (valid ? (nbase + i) : 0) * 16 + lm;
        float bv = valid ? b3[se * D3 + n3] : 0.f;
        float wv = valid ? W4[se * D3 + n3] : 0.f;
        #pragma unroll
        for (int r = 0; r < 4; ++r) {
            s0[r] += celu_f(acc3[0][i][r] + bv) * wv;
            s1[r] += celu_f(acc3[1][i][r] + bv) * wv;
            s2[r] += celu_f(acc3[2][i][r] + bv) * wv;
            s3[r] += celu_f(acc3[3][i][r] + bv) * wv;
        }
    }
    // butterfly over the 16-lane (lm) group: every lane ends with all 16 group sums
    #pragma unroll
    for (int o = 1; o <= 8; o <<= 1) {
        #pragma unroll
        for (int r = 0; r < 4; ++r) {
            s0[r] += __shfl_xor(s0[r], o);
            s1[r] += __shfl_xor(s1[r], o);
            s2[r] += __shfl_xor(s2[r], o);
            s3[r] += __shfl_xor(s3[r], o);
        }
    }
    // lane lm supplies row (mi=lm>>2, rr=lm&3) — static select tree, runtime only in address
    f32x4 sm = (lm & 8) ? ((lm & 4) ? s3 : s2) : ((lm & 4) ? s1 : s0);
    float v = (lm & 2) ? ((lm & 1) ? sm[3] : sm[2]) : ((lm & 1) ? sm[1] : sm[0]);

    float* red = (float*)Astb;              // rows 48..63 region; disjoint from H2 (rows 0..47)
    red[w * 64 + (lm >> 2) * 16 + kq * 4 + (lm & 3)] = v;
    __syncthreads();
    if (t < 64) {
        int a = t;
        float e = red[a] + red[64 + a] + red[128 + a] + red[192 + a];
        if (tile * TM + a >= NPS) e = 0.0f;
        #pragma unroll
        for (int o = 32; o > 0; o >>= 1) e += __shfl_xor(e, o);
        if (t == 0) {
            int nv = NPS - tile * TM; if (nv > TM) nv = TM;
            partials[tile * (S_ * E_) + se] = e + (float)nv * b4[se];
        }
    }
}

__global__ void reduce_partials(const float* __restrict__ p, int n, float* __restrict__ out)
{
    float s = 0.0f;
    for (int i = threadIdx.x; i < n; i += 256) s += p[i];
    #pragma unroll
    for (int o = 32; o > 0; o >>= 1) s += __shfl_xor(s, o);
    __shared__ float sm[4];
    if ((threadIdx.x & 63) == 0) sm[threadIdx.x >> 6] = s;
    __syncthreads();
    if (threadIdx.x == 0) out[0] = (sm[0] + sm[1] + sm[2] + sm[3]) * (1.0f / E_);
}

extern "C" void kernel_launch(void* const* d_in, const int* in_sizes, int n_in,
                              void* d_out, int out_size, void* d_ws, size_t ws_size,
                              hipStream_t stream)
{
    const float* aev = (const float*)d_in[0];
    const int*   idx = (const int*)  d_in[2];
    const float* W1  = (const float*)d_in[3];
    const float* b1  = (const float*)d_in[4];
    const float* W2  = (const float*)d_in[5];
    const float* b2  = (const float*)d_in[6];
    const float* W3  = (const float*)d_in[7];
    const float* b3  = (const float*)d_in[8];
    const float* W4  = (const float*)d_in[9];
    const float* b4  = (const float*)d_in[10];
    float* out = (float*)d_out;

    ushort* w1p = (ushort*)d_ws;
    ushort* w2p = w1p + (size_t)S_ * E_ * KB1 * NB1 * 512;
    ushort* w3p = w2p + (size_t)S_ * E_ * KB2 * NB2 * 512;
    float* partials = (float*)(w3p + (size_t)S_ * E_ * KB3 * NB3 * 512);
    ushort* aevb = (ushort*)(partials + NT * S_ * E_);   // 102.8 MB gathered bf16 aev

    prep<<<PACKB + GATB, 256, 0, stream>>>(W1, W2, W3, w1p, w2p, w3p, aev, idx, aevb);

    dim3 grid(32 * TG, NG);   // supertile: 8 tiles x (4 e x 8 XCD) per group; XCD species-pure
    ani_mfma<<<grid, 256, 0, stream>>>(aevb, w1p, w2p, w3p,
                                       b1, b2, b3, W4, b4, partials);
    reduce_partials<<<1, 256, 0, stream>>>(partials, NT * S_ * E_, out);
}